// Round 4
// baseline (139.915 us; speedup 1.0000x reference)
//
#include <hip/hip_runtime.h>
#include <math.h>

#define Bq 4
#define Cq 64
#define Hq 160
#define Wq 160
#define HWq (Hq*Wq)      // 25600
#define OUTq 64
#define KKq 576          // Cq*9
#define KS  18           // KKq/32
#define SROW 584         // padded kk row (fp16 units); 1168 B, rows 16B-aligned
#define HSTRIDE 72       // halo px stride (ushorts) = 144 B
#define HROWPX 20        // halo px per row (j0-2 .. j0+17)
#define HROWS  5         // halo rows (i-2 .. i+2)
#define HALO_B (HROWS*HROWPX*HSTRIDE*2)   // 14,400 B

typedef __attribute__((ext_vector_type(8))) _Float16 half8;
typedef __attribute__((ext_vector_type(2))) _Float16 half2v;
typedef __attribute__((ext_vector_type(4))) float float4v;
typedef __attribute__((ext_vector_type(4))) unsigned short ushort4v;
typedef unsigned short ushort_t;
typedef unsigned int uint_t;

__device__ __forceinline__ ushort_t f2h(float f) {          // RNE f32->f16
    return __builtin_bit_cast(ushort_t, (_Float16)f);
}
__device__ __forceinline__ uint_t f2hdup(float f) {         // (h,h) packed
    uint_t u = (uint_t)f2h(f);
    return u | (u << 16);
}
__device__ __forceinline__ half2v h2(uint_t u) {
    return __builtin_bit_cast(half2v, u);
}
#define MFMA16(a,b,c) __builtin_amdgcn_mfma_f32_16x16x32_f16((a),(b),(c),0,0,0)

// ---------------------------------------------------------------------------
// K_prep: x NCHW f32 -> xt NHWC fp16; weight prepack on first 216 blocks.
// ---------------------------------------------------------------------------
__global__ void __launch_bounds__(256) k_prep(const float* __restrict__ x,
                                              const float* __restrict__ dcn_w,
                                              const float* __restrict__ off_w,
                                              const float* __restrict__ msk_w,
                                              ushort_t* __restrict__ xt,
                                              ushort_t* __restrict__ wtf,
                                              ushort_t* __restrict__ cwf2) {
    __shared__ float tile[64][65];
    int b = blockIdx.y, hw0 = blockIdx.x * 64;
    int tid = threadIdx.x;
    int l16 = tid & 15, crow = tid >> 4;        // crow 0..15
#pragma unroll
    for (int i = 0; i < 4; ++i) {
        int c = crow + i*16;
        float4 v = *(const float4*)(x + ((size_t)(b*Cq + c))*HWq + hw0 + l16*4);
        tile[c][l16*4+0] = v.x;
        tile[c][l16*4+1] = v.y;
        tile[c][l16*4+2] = v.z;
        tile[c][l16*4+3] = v.w;
    }
    __syncthreads();
#pragma unroll
    for (int it = 0; it < 4; ++it) {
        int hw = (tid >> 4) + it*16;
        int c4 = (tid & 15) * 4;
        uint_t v0 = (uint_t)f2h(tile[c4+0][hw]) | ((uint_t)f2h(tile[c4+1][hw]) << 16);
        uint_t v1 = (uint_t)f2h(tile[c4+2][hw]) | ((uint_t)f2h(tile[c4+3][hw]) << 16);
        uint2 vv; vv.x = v0; vv.y = v1;
        *(uint2*)(xt + ((size_t)b*HWq + hw0 + hw)*64 + c4) = vv;
    }
    if (blockIdx.y == 0 && blockIdx.x < 216) {
        int id = blockIdx.x*256 + tid;
        if (id < 4*KS*512) {
            int j = id & 7, ln = (id>>3) & 63, ks = (id>>9) % KS, g = id/(512*KS);
            int kk = ks*32 + (ln>>4)*8 + j;
            int c  = kk & 63, kt = kk >> 6;
            int m  = g*16 + (ln&15);
            wtf[id] = f2h(dcn_w[m*KKq + c*9 + kt]);
        }
        int id2 = id - 4*KS*512;
        if (id2 >= 0 && id2 < 9*2*2*512) {
            int j = id2 & 7, ln = (id2>>3) & 63;
            int ks2 = (id2>>9) & 1, g = (id2>>10) & 1, k = id2 >> 11;
            int co = g*16 + (ln&15);
            int c  = ks2*32 + (ln>>4)*8 + j;
            float w = 0.f;
            if (co < 18)      w = off_w[co*KKq + c*9 + k];
            else if (co < 27) w = msk_w[(co-18)*KKq + c*9 + k];
            cwf2[id2] = f2h(w);
        }
    }
}

// ---------------------------------------------------------------------------
// K_fused: halo 5x20 px (covers all bilinear corners for |offset|<1) ->
//  offset/mask conv (f16 MFMA) -> tap descriptors: u16 LDS byte-offsets
//  (bit15=0) or global px index (bit15=1 fallback, |offset|>=1, ~never) ->
//  Phase B sampling from LDS (half-wave per (p,tap), 2 ch/lane, ds_read_b32
//  gathers, pk_fma_f16) -> Phase C f16 MFMA matmul -> store.
// LDS: halo(14400) + union{s_part(4096) | s_s(18688)} + s_A16(1152) + s_W(2304)
//    = 36,544 B -> 4 blocks/CU (occupancy ~50%, perf-neutral per r0/r3 A/B).
// ---------------------------------------------------------------------------
__global__ void __launch_bounds__(256, 4) k_fused(const ushort_t* __restrict__ xt,
                                                  const ushort_t* __restrict__ cwf2,
                                                  const float* __restrict__ off_b,
                                                  const float* __restrict__ msk_b,
                                                  const ushort_t* __restrict__ wtf,
                                                  float* __restrict__ out) {
    __shared__ __align__(16) char s_mem[HALO_B + 16*SROW*2]; // 14,400 + 18,688
    __shared__ __align__(16) ushort4v s_A16[144];            //  1,152 B
    __shared__ __align__(16) uint4 s_W[144];                 //  2,304 B
    ushort_t* halo   = (ushort_t*)s_mem;                     // [0, 14400)
    float*    s_part = (float*)(s_mem + HALO_B);             // conv partials
    ushort_t* s_s    = (ushort_t*)(s_mem + HALO_B);          // Phase B/C

    int blk = blockIdx.x;                 // 6400 = 4 * 160 * 10
    int jt = blk % 10, i = (blk/10) % Hq, b = blk/(10*Hq);
    int j0 = jt*16;
    int tid = threadIdx.x, lane = tid & 63, grp = tid >> 6;
    int n = lane & 15, quad = lane >> 4;

    // ---- Stage halo: 5 rows x 20 px x 64 ch fp16 ----
    const ushort_t* xtb = xt + (size_t)b*HWq*64;
    for (int t = tid; t < HROWS*HROWPX*8; t += 256) {
        int seg = t >> 3, sub = t & 7;
        int r = seg / HROWPX, px = seg % HROWPX;
        int y = i + r - 2, xx = j0 + px - 2;
        uint4 v = {0u,0u,0u,0u};
        if ((unsigned)y < (unsigned)Hq && (unsigned)xx < (unsigned)Wq)
            v = *(const uint4*)(xtb + ((size_t)y*Wq + xx)*64 + sub*8);
        *(uint4*)(halo + (r*HROWPX + px)*HSTRIDE + sub*8) = v;
    }
    __syncthreads();

    // ---- Offset/mask conv: wave (gM, kh) over 9 K-steps each ----
    {
        int gM = grp & 1, kh = grp >> 1;
        float4v cacc = {0.f,0.f,0.f,0.f};
#pragma unroll
        for (int s = 0; s < 9; ++s) {
            int st = kh*9 + s;            // 0..17
            int k = st >> 1, ks2 = st & 1;
            int ky = k/3, kx = k - (k/3)*3;
            half8 a  = *(const half8*)(cwf2 + (size_t)(((k*2+gM)*2+ks2)*512 + lane*8));
            half8 bf = *(const half8*)(halo + ((ky+1)*HROWPX + (n + kx + 1))*HSTRIDE + quad*8 + ks2*32);
            cacc = MFMA16(a, bf, cacc);
        }
        *(float4v*)(s_part + grp*256 + lane*4) = cacc;
    }
    __syncthreads();

    // ---- Phase A: tap descriptors from conv partials ----
    if (tid < 144) {
        int p = tid & 15, k = tid >> 4;
        #define RD(co) (s_part[(((co)>>4)*256)     + ((((co)&15)>>2)*16 + p)*4 + ((co)&3)] + \
                        s_part[(2 + ((co)>>4))*256 + ((((co)&15)>>2)*16 + p)*4 + ((co)&3)])
        float oy = RD(2*k)   + off_b[2*k];
        float ox = RD(2*k+1) + off_b[2*k+1];
        float mv = RD(18+k)  + msk_b[k];
        #undef RD
        float m = 1.f/(1.f + __expf(-mv));
        float py = oy + (float)(i - 1 + k/3);
        float px = ox + (float)(j0 + p - 1 + (k - (k/3)*3));
        float fy = floorf(py), fx = floorf(px);
        int y0 = (int)fy, x0 = (int)fx;
        float wy1 = py - fy, wx1 = px - fx;
        float wy0 = 1.f - wy1, wx0 = 1.f - wx1;
        bool vy0 = (y0 >= 0) & (y0 < Hq),   vy1 = (y0+1 >= 0) & (y0+1 < Hq);
        bool vx0 = (x0 >= 0) & (x0 < Wq),   vx1 = (x0+1 >= 0) & (x0+1 < Wq);
        int yc0 = min(max(y0,   0), Hq-1), yc1 = min(max(y0+1, 0), Hq-1);
        int xc0 = min(max(x0,   0), Wq-1), xc1 = min(max(x0+1, 0), Wq-1);
        ushort4v av;
        bool inh = (yc0 >= i-2) && (yc1 <= i+2) && (xc0 >= j0-2) && (xc1 <= j0+17);
        if (inh) {
            // LDS byte offsets into halo (max (4*20+19)*144 = 14,256 < 2^15)
            int ry0 = (yc0 - (i-2)) * (HROWPX*HSTRIDE*2);
            int ry1 = (yc1 - (i-2)) * (HROWPX*HSTRIDE*2);
            int cx0 = (xc0 - (j0-2)) * (HSTRIDE*2);
            int cx1 = (xc1 - (j0-2)) * (HSTRIDE*2);
            av.x = (ushort_t)(ry0 + cx0);
            av.y = (ushort_t)(ry0 + cx1);
            av.z = (ushort_t)(ry1 + cx0);
            av.w = (ushort_t)(ry1 + cx1);
        } else {
            // global pixel index, bit15 = fallback marker (idx <= 25599 < 2^15)
            av.x = (ushort_t)((yc0*Wq + xc0) | 0x8000);
            av.y = (ushort_t)((yc0*Wq + xc1) | 0x8000);
            av.z = (ushort_t)((yc1*Wq + xc0) | 0x8000);
            av.w = (ushort_t)((yc1*Wq + xc1) | 0x8000);
        }
        s_A16[tid] = av;
        s_W[tid] = make_uint4(f2hdup((vy0 && vx0) ? wy0*wx0*m : 0.f),
                              f2hdup((vy0 && vx1) ? wy0*wx1*m : 0.f),
                              f2hdup((vy1 && vx0) ? wy1*wx0*m : 0.f),
                              f2hdup((vy1 && vx1) ? wy1*wx1*m : 0.f));
    }
    __syncthreads();

    // ---- Phase B: half-wave per (p,tap), 2 ch/lane, LDS gathers ----
    {
        int lane4 = (lane & 31) * 4;
        int halfi = lane >> 5;
        const char* xtbB = (const char*)xtb;
        const char* haloB = (const char*)s_mem;
        char* s_sb = (char*)s_s;
#pragma unroll 2
        for (int iter = 0; iter < 18; ++iter) {
            int t2h = iter*8 + grp*2 + halfi;
            uint2 Ad = *(const uint2*)(&s_A16[t2h]);
            uint4 Wt = s_W[t2h];
            uint_t a0 = Ad.x & 0xffffu, a1 = Ad.x >> 16;
            uint_t a2 = Ad.y & 0xffffu, a3 = Ad.y >> 16;
            uint_t dst = (uint_t)((t2h & 15)*(SROW*2) + (t2h >> 4)*128);
            uint_t u00, u01, u10, u11;
            if (a0 < 0x8000u) {          // LDS path (normal case)
                u00 = *(const uint_t*)(haloB + a0 + lane4);
                u01 = *(const uint_t*)(haloB + a1 + lane4);
                u10 = *(const uint_t*)(haloB + a2 + lane4);
                u11 = *(const uint_t*)(haloB + a3 + lane4);
            } else {                     // global fallback (|offset| >= 1)
                u00 = *(const uint_t*)(xtbB + ((a0 & 0x7fffu) << 7) + lane4);
                u01 = *(const uint_t*)(xtbB + ((a1 & 0x7fffu) << 7) + lane4);
                u10 = *(const uint_t*)(xtbB + ((a2 & 0x7fffu) << 7) + lane4);
                u11 = *(const uint_t*)(xtbB + ((a3 & 0x7fffu) << 7) + lane4);
            }
            half2v acc2 = h2(u00) * h2(Wt.x);
            acc2 = __builtin_elementwise_fma(h2(u01), h2(Wt.y), acc2);
            acc2 = __builtin_elementwise_fma(h2(u10), h2(Wt.z), acc2);
            acc2 = __builtin_elementwise_fma(h2(u11), h2(Wt.w), acc2);
            *(uint_t*)(s_sb + dst + lane4) = __builtin_bit_cast(uint_t, acc2);
        }
    }
    __syncthreads();

    // ---- Phase C: wave grp -> o rows [grp*16, +16), 16 pixels ----
    float4v acc = {0.f,0.f,0.f,0.f};
    const ushort_t* arow = wtf + ((size_t)(grp*KS)*64 + lane)*8;
    const ushort_t* brow = s_s + n*SROW + quad*8;
#pragma unroll
    for (int ks = 0; ks < KS; ++ks) {
        half8 a  = *(const half8*)(arow + ks*512);
        half8 bf = *(const half8*)(brow + ks*32);
        acc = MFMA16(a, bf, acc);
    }

#pragma unroll
    for (int r = 0; r < 4; ++r) {
        int o = grp*16 + quad*4 + r;
        out[(((size_t)b*OUTq + o)*Hq + i)*Wq + j0 + n] = acc[r];
    }
}

// ---------------------------------------------------------------------------
extern "C" void kernel_launch(void* const* d_in, const int* in_sizes, int n_in,
                              void* d_out, int out_size, void* d_ws, size_t ws_size,
                              hipStream_t stream) {
    const float* x     = (const float*)d_in[0];
    const float* off_w = (const float*)d_in[1];
    const float* off_b = (const float*)d_in[2];
    const float* msk_w = (const float*)d_in[3];
    const float* msk_b = (const float*)d_in[4];
    const float* dcn_w = (const float*)d_in[5];
    float* out = (float*)d_out;

    char* ws = (char*)d_ws;
    ushort_t* xt   = (ushort_t*)ws;                  // 13,107,200 B
    ushort_t* wtf  = xt + (size_t)Bq*HWq*64;         //     73,728 B
    ushort_t* cwf2 = wtf + 4*KS*512;                 //     36,864 B

    hipLaunchKernelGGL(k_prep, dim3(HWq/64, Bq), dim3(256), 0, stream,
                       x, dcn_w, off_w, msk_w, xt, wtf, cwf2);
    hipLaunchKernelGGL(k_fused, dim3(Bq*Hq*10), dim3(256), 0, stream,
                       xt, cwf2, off_b, msk_b, wtf, out);
}

// Round 5
// 130.926 us; speedup vs baseline: 1.0687x; 1.0687x over previous
//
#include <hip/hip_runtime.h>
#include <math.h>

#define Bq 4
#define Cq 64
#define Hq 160
#define Wq 160
#define HWq (Hq*Wq)      // 25600
#define OUTq 64
#define KKq 576          // Cq*9
#define KS  18           // KKq/32
#define SROW 584         // padded kk row (fp16 units); 1168 B, rows 16B-aligned
#define HSTRIDE 72       // halo px stride (ushorts) = 144 B

typedef __attribute__((ext_vector_type(8))) _Float16 half8;
typedef __attribute__((ext_vector_type(2))) _Float16 half2v;
typedef __attribute__((ext_vector_type(4))) float float4v;
typedef __attribute__((ext_vector_type(4))) unsigned short ushort4v;
typedef unsigned short ushort_t;
typedef unsigned int uint_t;

__device__ __forceinline__ ushort_t f2h(float f) {          // RNE f32->f16
    return __builtin_bit_cast(ushort_t, (_Float16)f);
}
__device__ __forceinline__ uint_t f2hdup(float f) {         // (h,h) packed
    uint_t u = (uint_t)f2h(f);
    return u | (u << 16);
}
__device__ __forceinline__ half2v h2(uint_t u) {
    return __builtin_bit_cast(half2v, u);
}
#define MFMA16(a,b,c) __builtin_amdgcn_mfma_f32_16x16x32_f16((a),(b),(c),0,0,0)

// ---------------------------------------------------------------------------
// K_prep: x NCHW f32 -> xt NHWC fp16; weight prepack on first 216 blocks.
//  Vectorized: float4 global loads, uint2 (4-ch) packed stores.
//  tile[64][65]: stride-65 floats => all LDS accesses <=2-way (free).
// ---------------------------------------------------------------------------
__global__ void __launch_bounds__(256) k_prep(const float* __restrict__ x,
                                              const float* __restrict__ dcn_w,
                                              const float* __restrict__ off_w,
                                              const float* __restrict__ msk_w,
                                              ushort_t* __restrict__ xt,
                                              ushort_t* __restrict__ wtf,
                                              ushort_t* __restrict__ cwf2) {
    __shared__ float tile[64][65];
    int b = blockIdx.y, hw0 = blockIdx.x * 64;
    int tid = threadIdx.x;
    int l16 = tid & 15, crow = tid >> 4;        // crow 0..15
#pragma unroll
    for (int i = 0; i < 4; ++i) {
        int c = crow + i*16;
        float4 v = *(const float4*)(x + ((size_t)(b*Cq + c))*HWq + hw0 + l16*4);
        tile[c][l16*4+0] = v.x;
        tile[c][l16*4+1] = v.y;
        tile[c][l16*4+2] = v.z;
        tile[c][l16*4+3] = v.w;
    }
    __syncthreads();
#pragma unroll
    for (int it = 0; it < 4; ++it) {
        int hw = (tid >> 4) + it*16;
        int c4 = (tid & 15) * 4;
        uint_t v0 = (uint_t)f2h(tile[c4+0][hw]) | ((uint_t)f2h(tile[c4+1][hw]) << 16);
        uint_t v1 = (uint_t)f2h(tile[c4+2][hw]) | ((uint_t)f2h(tile[c4+3][hw]) << 16);
        uint2 vv; vv.x = v0; vv.y = v1;
        *(uint2*)(xt + ((size_t)b*HWq + hw0 + hw)*64 + c4) = vv;
    }
    if (blockIdx.y == 0 && blockIdx.x < 216) {
        int id = blockIdx.x*256 + tid;
        if (id < 4*KS*512) {
            int j = id & 7, ln = (id>>3) & 63, ks = (id>>9) % KS, g = id/(512*KS);
            int kk = ks*32 + (ln>>4)*8 + j;
            int c  = kk & 63, kt = kk >> 6;
            int m  = g*16 + (ln&15);
            wtf[id] = f2h(dcn_w[m*KKq + c*9 + kt]);
        }
        int id2 = id - 4*KS*512;
        if (id2 >= 0 && id2 < 9*2*2*512) {
            int j = id2 & 7, ln = (id2>>3) & 63;
            int ks2 = (id2>>9) & 1, g = (id2>>10) & 1, k = id2 >> 11;
            int co = g*16 + (ln&15);
            int c  = ks2*32 + (ln>>4)*8 + j;
            float w = 0.f;
            if (co < 18)      w = off_w[co*KKq + c*9 + k];
            else if (co < 27) w = msk_w[(co-18)*KKq + c*9 + k];
            cwf2[id2] = f2h(w);
        }
    }
}

// ---------------------------------------------------------------------------
// K_fused (r3 structure + XCD-aware block swizzle):
//  blk = (bid&7)*800 + bid>>3  -- 6400%8==0 so this is bijective.
//  Each XCD owns a contiguous (b, 80-row) band: xt working set 1.6 MB
//  fits the per-XCD 4 MB L2, so halo rows (3x reuse) and Phase-B gather
//  corners become L2 hits instead of cross-XCD HBM misses.
//  Phases: halo stage -> offset/mask conv (f16 MFMA) -> tap descriptors
//  (u16 pixel indices, <<7 at use; duplicated-fp16 premasked weights)
//  -> Phase B sampling (half-wave per (p,tap), 2 ch/lane, dword gathers,
//  pure v_pk_fma_f16) -> Phase C f16 MFMA matmul -> store.
// LDS: union{halo(7776)+partials(4096) | s_s(18688)} + s_A16(1152) + s_W(2304)
//    = 22144 B -> 7 blocks/CU.
// ---------------------------------------------------------------------------
__global__ void __launch_bounds__(256, 7) k_fused(const ushort_t* __restrict__ xt,
                                                  const ushort_t* __restrict__ cwf2,
                                                  const float* __restrict__ off_b,
                                                  const float* __restrict__ msk_b,
                                                  const ushort_t* __restrict__ wtf,
                                                  float* __restrict__ out) {
    __shared__ __align__(16) char s_mem[16*SROW*2];          // 18,688 B
    __shared__ __align__(16) ushort4v s_A16[144];            //  1,152 B
    __shared__ __align__(16) uint4 s_W[144];                 //  2,304 B
    ushort_t* halo   = (ushort_t*)s_mem;                     // [0, 7776)
    float*    s_part = (float*)(s_mem + 7776);               // [7776, 11872)
    ushort_t* s_s    = (ushort_t*)s_mem;                     // Phase B/C

    // XCD-aware swizzle: consecutive hardware wgids round-robin the 8 XCDs;
    // give each XCD a contiguous 800-block chunk of the logical raster order.
    int bid = blockIdx.x;                 // 6400 = 4 * 160 * 10
    int blk = (bid & 7) * 800 + (bid >> 3);
    int jt = blk % 10, i = (blk/10) % Hq, b = blk/(10*Hq);
    int j0 = jt*16;
    int tid = threadIdx.x, lane = tid & 63, grp = tid >> 6;
    int n = lane & 15, quad = lane >> 4;

    // ---- Stage halo: 3 rows x 18 px x 64 ch fp16 ----
    const ushort_t* xtb = xt + (size_t)b*HWq*64;
    for (int t = tid; t < 432; t += 256) {
        int seg = t >> 3, sub = t & 7;
        int ky = seg / 18, px = seg % 18;
        int y = i + ky - 1, xx = j0 + px - 1;
        uint4 v = {0u,0u,0u,0u};
        if (y >= 0 && y < Hq && xx >= 0 && xx < Wq)
            v = *(const uint4*)(xtb + ((size_t)y*Wq + xx)*64 + sub*8);
        *(uint4*)(halo + (ky*18 + px)*HSTRIDE + sub*8) = v;
    }
    __syncthreads();

    // ---- Offset/mask conv: wave (gM, kh) over 9 K-steps each ----
    {
        int gM = grp & 1, kh = grp >> 1;
        float4v cacc = {0.f,0.f,0.f,0.f};
#pragma unroll
        for (int s = 0; s < 9; ++s) {
            int st = kh*9 + s;            // 0..17
            int k = st >> 1, ks2 = st & 1;
            int ky = k/3, kx = k - (k/3)*3;
            half8 a  = *(const half8*)(cwf2 + (size_t)(((k*2+gM)*2+ks2)*512 + lane*8));
            half8 bf = *(const half8*)(halo + (ky*18 + n + kx)*HSTRIDE + quad*8 + ks2*32);
            cacc = MFMA16(a, bf, cacc);
        }
        *(float4v*)(s_part + grp*256 + lane*4) = cacc;
    }
    __syncthreads();

    // ---- Phase A: tap descriptors from conv partials ----
    if (tid < 144) {
        int p = tid & 15, k = tid >> 4;
        #define RD(co) (s_part[(((co)>>4)*256)     + ((((co)&15)>>2)*16 + p)*4 + ((co)&3)] + \
                        s_part[(2 + ((co)>>4))*256 + ((((co)&15)>>2)*16 + p)*4 + ((co)&3)])
        float oy = RD(2*k)   + off_b[2*k];
        float ox = RD(2*k+1) + off_b[2*k+1];
        float mv = RD(18+k)  + msk_b[k];
        #undef RD
        float m = 1.f/(1.f + __expf(-mv));
        float py = oy + (float)(i - 1 + k/3);
        float px = ox + (float)(j0 + p - 1 + (k - (k/3)*3));
        float fy = floorf(py), fx = floorf(px);
        int y0 = (int)fy, x0 = (int)fx;
        float wy1 = py - fy, wx1 = px - fx;
        float wy0 = 1.f - wy1, wx0 = 1.f - wx1;
        bool vy0 = (y0 >= 0) & (y0 < Hq),   vy1 = (y0+1 >= 0) & (y0+1 < Hq);
        bool vx0 = (x0 >= 0) & (x0 < Wq),   vx1 = (x0+1 >= 0) & (x0+1 < Wq);
        int yc0 = min(max(y0,   0), Hq-1), yc1 = min(max(y0+1, 0), Hq-1);
        int xc0 = min(max(x0,   0), Wq-1), xc1 = min(max(x0+1, 0), Wq-1);
        ushort4v av;
        av.x = (ushort_t)(yc0*Wq + xc0);
        av.y = (ushort_t)(yc0*Wq + xc1);
        av.z = (ushort_t)(yc1*Wq + xc0);
        av.w = (ushort_t)(yc1*Wq + xc1);
        s_A16[tid] = av;
        s_W[tid] = make_uint4(f2hdup((vy0 && vx0) ? wy0*wx0*m : 0.f),
                              f2hdup((vy0 && vx1) ? wy0*wx1*m : 0.f),
                              f2hdup((vy1 && vx0) ? wy1*wx0*m : 0.f),
                              f2hdup((vy1 && vx1) ? wy1*wx1*m : 0.f));
    }
    __syncthreads();

    // ---- Phase B: half-wave per (p,tap), 2 ch/lane, pk_fma_f16 ----
    {
        int lane4 = (lane & 31) * 4;
        int halfi = lane >> 5;
        const char* xtbB = (const char*)xtb;
        char* s_sb = (char*)s_s;
#pragma unroll 2
        for (int iter = 0; iter < 18; ++iter) {
            int t2h = iter*8 + grp*2 + halfi;
            ushort4v A = s_A16[t2h];
            uint4 Wt   = s_W[t2h];
            uint_t dst = (uint_t)((t2h & 15)*(SROW*2) + (t2h >> 4)*128);
            uint_t u00 = *(const uint_t*)(xtbB + (((uint_t)A.x) << 7) + lane4);
            uint_t u01 = *(const uint_t*)(xtbB + (((uint_t)A.y) << 7) + lane4);
            uint_t u10 = *(const uint_t*)(xtbB + (((uint_t)A.z) << 7) + lane4);
            uint_t u11 = *(const uint_t*)(xtbB + (((uint_t)A.w) << 7) + lane4);
            half2v acc2 = h2(u00) * h2(Wt.x);
            acc2 = __builtin_elementwise_fma(h2(u01), h2(Wt.y), acc2);
            acc2 = __builtin_elementwise_fma(h2(u10), h2(Wt.z), acc2);
            acc2 = __builtin_elementwise_fma(h2(u11), h2(Wt.w), acc2);
            *(uint_t*)(s_sb + dst + lane4) = __builtin_bit_cast(uint_t, acc2);
        }
    }
    __syncthreads();

    // ---- Phase C: wave grp -> o rows [grp*16, +16), 16 pixels ----
    float4v acc = {0.f,0.f,0.f,0.f};
    const ushort_t* arow = wtf + ((size_t)(grp*KS)*64 + lane)*8;
    const ushort_t* brow = s_s + n*SROW + quad*8;
#pragma unroll
    for (int ks = 0; ks < KS; ++ks) {
        half8 a  = *(const half8*)(arow + ks*512);
        half8 bf = *(const half8*)(brow + ks*32);
        acc = MFMA16(a, bf, acc);
    }

#pragma unroll
    for (int r = 0; r < 4; ++r) {
        int o = grp*16 + quad*4 + r;
        out[(((size_t)b*OUTq + o)*Hq + i)*Wq + j0 + n] = acc[r];
    }
}

// ---------------------------------------------------------------------------
extern "C" void kernel_launch(void* const* d_in, const int* in_sizes, int n_in,
                              void* d_out, int out_size, void* d_ws, size_t ws_size,
                              hipStream_t stream) {
    const float* x     = (const float*)d_in[0];
    const float* off_w = (const float*)d_in[1];
    const float* off_b = (const float*)d_in[2];
    const float* msk_w = (const float*)d_in[3];
    const float* msk_b = (const float*)d_in[4];
    const float* dcn_w = (const float*)d_in[5];
    float* out = (float*)d_out;

    char* ws = (char*)d_ws;
    ushort_t* xt   = (ushort_t*)ws;                  // 13,107,200 B
    ushort_t* wtf  = xt + (size_t)Bq*HWq*64;         //     73,728 B
    ushort_t* cwf2 = wtf + 4*KS*512;                 //     36,864 B

    hipLaunchKernelGGL(k_prep, dim3(HWq/64, Bq), dim3(256), 0, stream,
                       x, dcn_w, off_w, msk_w, xt, wtf, cwf2);
    hipLaunchKernelGGL(k_fused, dim3(Bq*Hq*10), dim3(256), 0, stream,
                       xt, cwf2, off_b, msk_b, wtf, out);
}

// Round 6
// 126.475 us; speedup vs baseline: 1.1063x; 1.0352x over previous
//
#include <hip/hip_runtime.h>
#include <math.h>

#define Bq 4
#define Cq 64
#define Hq 160
#define Wq 160
#define HWq (Hq*Wq)      // 25600
#define OUTq 64
#define KKq 576          // Cq*9
#define KS  18           // KKq/32
#define SROW 584         // padded kk row (fp16 units); 1168 B, rows 16B-aligned
#define HSTRIDE 72       // halo px stride (ushorts) = 144 B

typedef __attribute__((ext_vector_type(8))) _Float16 half8;
typedef __attribute__((ext_vector_type(2))) _Float16 half2v;
typedef __attribute__((ext_vector_type(4))) float float4v;
typedef __attribute__((ext_vector_type(4))) unsigned short ushort4v;
typedef unsigned short ushort_t;
typedef unsigned int uint_t;

__device__ __forceinline__ ushort_t f2h(float f) {          // RNE f32->f16
    return __builtin_bit_cast(ushort_t, (_Float16)f);
}
__device__ __forceinline__ uint_t f2hdup(float f) {         // (h,h) packed
    uint_t u = (uint_t)f2h(f);
    return u | (u << 16);
}
__device__ __forceinline__ half2v h2(uint_t u) {
    return __builtin_bit_cast(half2v, u);
}
#define MFMA16(a,b,c) __builtin_amdgcn_mfma_f32_16x16x32_f16((a),(b),(c),0,0,0)

// ---------------------------------------------------------------------------
// K_prep: x NCHW f32 -> xt NHWC fp16; weight prepack on first 216 blocks.
//  Vectorized: float4 global loads, uint2 (4-ch) packed stores.
//  tile[64][65]: stride-65 floats => all LDS accesses <=2-way (free).
// ---------------------------------------------------------------------------
__global__ void __launch_bounds__(256) k_prep(const float* __restrict__ x,
                                              const float* __restrict__ dcn_w,
                                              const float* __restrict__ off_w,
                                              const float* __restrict__ msk_w,
                                              ushort_t* __restrict__ xt,
                                              ushort_t* __restrict__ wtf,
                                              ushort_t* __restrict__ cwf2) {
    __shared__ float tile[64][65];
    int b = blockIdx.y, hw0 = blockIdx.x * 64;
    int tid = threadIdx.x;
    int l16 = tid & 15, crow = tid >> 4;        // crow 0..15
#pragma unroll
    for (int i = 0; i < 4; ++i) {
        int c = crow + i*16;
        float4 v = *(const float4*)(x + ((size_t)(b*Cq + c))*HWq + hw0 + l16*4);
        tile[c][l16*4+0] = v.x;
        tile[c][l16*4+1] = v.y;
        tile[c][l16*4+2] = v.z;
        tile[c][l16*4+3] = v.w;
    }
    __syncthreads();
#pragma unroll
    for (int it = 0; it < 4; ++it) {
        int hw = (tid >> 4) + it*16;
        int c4 = (tid & 15) * 4;
        uint_t v0 = (uint_t)f2h(tile[c4+0][hw]) | ((uint_t)f2h(tile[c4+1][hw]) << 16);
        uint_t v1 = (uint_t)f2h(tile[c4+2][hw]) | ((uint_t)f2h(tile[c4+3][hw]) << 16);
        uint2 vv; vv.x = v0; vv.y = v1;
        *(uint2*)(xt + ((size_t)b*HWq + hw0 + hw)*64 + c4) = vv;
    }
    if (blockIdx.y == 0 && blockIdx.x < 216) {
        int id = blockIdx.x*256 + tid;
        if (id < 4*KS*512) {
            int j = id & 7, ln = (id>>3) & 63, ks = (id>>9) % KS, g = id/(512*KS);
            int kk = ks*32 + (ln>>4)*8 + j;
            int c  = kk & 63, kt = kk >> 6;
            int m  = g*16 + (ln&15);
            wtf[id] = f2h(dcn_w[m*KKq + c*9 + kt]);
        }
        int id2 = id - 4*KS*512;
        if (id2 >= 0 && id2 < 9*2*2*512) {
            int j = id2 & 7, ln = (id2>>3) & 63;
            int ks2 = (id2>>9) & 1, g = (id2>>10) & 1, k = id2 >> 11;
            int co = g*16 + (ln&15);
            int c  = ks2*32 + (ln>>4)*8 + j;
            float w = 0.f;
            if (co < 18)      w = off_w[co*KKq + c*9 + k];
            else if (co < 27) w = msk_w[(co-18)*KKq + c*9 + k];
            cwf2[id2] = f2h(w);
        }
    }
}

// ---------------------------------------------------------------------------
// K_fused (r5 base: XCD swizzle kept) + ILP round:
//  - conv a-frags (cwf2) hoisted ABOVE the halo barrier (L2 latency hidden
//    under the barrier wait; conv phase is pure LDS+MFMA)
//  - Phase B: 1-deep software pipeline (desc read + 4 gathers for iter k+1
//    issued before the FMAs of iter k)
//  - Phase C: a-row prefetch 1-deep
//  launch_bounds (256,6): 85-VGPR budget for the in-flight loads; LDS 22144
//  still allows 7 blocks/CU if VGPR <= 73 (6<->7 proven perf-neutral r0/r3).
// ---------------------------------------------------------------------------
__global__ void __launch_bounds__(256, 6) k_fused(const ushort_t* __restrict__ xt,
                                                  const ushort_t* __restrict__ cwf2,
                                                  const float* __restrict__ off_b,
                                                  const float* __restrict__ msk_b,
                                                  const ushort_t* __restrict__ wtf,
                                                  float* __restrict__ out) {
    __shared__ __align__(16) char s_mem[16*SROW*2];          // 18,688 B
    __shared__ __align__(16) ushort4v s_A16[144];            //  1,152 B
    __shared__ __align__(16) uint4 s_W[144];                 //  2,304 B
    ushort_t* halo   = (ushort_t*)s_mem;                     // [0, 7776)
    float*    s_part = (float*)(s_mem + 7776);               // [7776, 11872)
    ushort_t* s_s    = (ushort_t*)s_mem;                     // Phase B/C

    // XCD-aware swizzle: consecutive hardware wgids round-robin the 8 XCDs;
    // give each XCD a contiguous 800-block chunk of the logical raster order.
    int bid = blockIdx.x;                 // 6400 = 4 * 160 * 10
    int blk = (bid & 7) * 800 + (bid >> 3);
    int jt = blk % 10, i = (blk/10) % Hq, b = blk/(10*Hq);
    int j0 = jt*16;
    int tid = threadIdx.x, lane = tid & 63, grp = tid >> 6;
    int n = lane & 15, quad = lane >> 4;

    // ---- Conv A-fragments: hoisted loads (independent of halo) ----
    int gM = grp & 1, kh = grp >> 1;
    half8 af[9];
#pragma unroll
    for (int s = 0; s < 9; ++s) {
        int st = kh*9 + s;                // 0..17
        int k = st >> 1, ks2 = st & 1;
        af[s] = *(const half8*)(cwf2 + (size_t)(((k*2+gM)*2+ks2)*512 + lane*8));
    }

    // ---- Stage halo: 3 rows x 18 px x 64 ch fp16 ----
    const ushort_t* xtb = xt + (size_t)b*HWq*64;
#pragma unroll
    for (int t = tid; t < 432; t += 256) {
        int seg = t >> 3, sub = t & 7;
        int ky = seg / 18, px = seg % 18;
        int y = i + ky - 1, xx = j0 + px - 1;
        uint4 v = {0u,0u,0u,0u};
        if (y >= 0 && y < Hq && xx >= 0 && xx < Wq)
            v = *(const uint4*)(xtb + ((size_t)y*Wq + xx)*64 + sub*8);
        *(uint4*)(halo + (ky*18 + px)*HSTRIDE + sub*8) = v;
    }
    __syncthreads();

    // ---- Offset/mask conv: wave (gM, kh) over 9 K-steps each ----
    {
        float4v cacc = {0.f,0.f,0.f,0.f};
#pragma unroll
        for (int s = 0; s < 9; ++s) {
            int st = kh*9 + s;            // 0..17
            int k = st >> 1, ks2 = st & 1;
            int ky = k/3, kx = k - (k/3)*3;
            half8 bf = *(const half8*)(halo + (ky*18 + n + kx)*HSTRIDE + quad*8 + ks2*32);
            cacc = MFMA16(af[s], bf, cacc);
        }
        *(float4v*)(s_part + grp*256 + lane*4) = cacc;
    }
    __syncthreads();

    // ---- Phase A: tap descriptors from conv partials ----
    if (tid < 144) {
        int p = tid & 15, k = tid >> 4;
        #define RD(co) (s_part[(((co)>>4)*256)     + ((((co)&15)>>2)*16 + p)*4 + ((co)&3)] + \
                        s_part[(2 + ((co)>>4))*256 + ((((co)&15)>>2)*16 + p)*4 + ((co)&3)])
        float oy = RD(2*k)   + off_b[2*k];
        float ox = RD(2*k+1) + off_b[2*k+1];
        float mv = RD(18+k)  + msk_b[k];
        #undef RD
        float m = 1.f/(1.f + __expf(-mv));
        float py = oy + (float)(i - 1 + k/3);
        float px = ox + (float)(j0 + p - 1 + (k - (k/3)*3));
        float fy = floorf(py), fx = floorf(px);
        int y0 = (int)fy, x0 = (int)fx;
        float wy1 = py - fy, wx1 = px - fx;
        float wy0 = 1.f - wy1, wx0 = 1.f - wx1;
        bool vy0 = (y0 >= 0) & (y0 < Hq),   vy1 = (y0+1 >= 0) & (y0+1 < Hq);
        bool vx0 = (x0 >= 0) & (x0 < Wq),   vx1 = (x0+1 >= 0) & (x0+1 < Wq);
        int yc0 = min(max(y0,   0), Hq-1), yc1 = min(max(y0+1, 0), Hq-1);
        int xc0 = min(max(x0,   0), Wq-1), xc1 = min(max(x0+1, 0), Wq-1);
        ushort4v av;
        av.x = (ushort_t)(yc0*Wq + xc0);
        av.y = (ushort_t)(yc0*Wq + xc1);
        av.z = (ushort_t)(yc1*Wq + xc0);
        av.w = (ushort_t)(yc1*Wq + xc1);
        s_A16[tid] = av;
        s_W[tid] = make_uint4(f2hdup((vy0 && vx0) ? wy0*wx0*m : 0.f),
                              f2hdup((vy0 && vx1) ? wy0*wx1*m : 0.f),
                              f2hdup((vy1 && vx0) ? wy1*wx0*m : 0.f),
                              f2hdup((vy1 && vx1) ? wy1*wx1*m : 0.f));
    }
    __syncthreads();

    // ---- Phase B: half-wave per (p,tap), 2 ch/lane, 1-deep pipelined ----
    {
        int lane4 = (lane & 31) * 4;
        int halfi = lane >> 5;
        const char* xtbB = (const char*)xtb;
        char* s_sb = (char*)s_s;
        int t2h = grp*2 + halfi;                 // task for iter 0
        ushort4v A = s_A16[t2h];
        uint4 Wt   = s_W[t2h];
        uint_t u00 = *(const uint_t*)(xtbB + (((uint_t)A.x) << 7) + lane4);
        uint_t u01 = *(const uint_t*)(xtbB + (((uint_t)A.y) << 7) + lane4);
        uint_t u10 = *(const uint_t*)(xtbB + (((uint_t)A.z) << 7) + lane4);
        uint_t u11 = *(const uint_t*)(xtbB + (((uint_t)A.w) << 7) + lane4);
#pragma unroll
        for (int iter = 0; iter < 18; ++iter) {
            int t_cur = t2h;
            uint4 Wc = Wt;
            uint_t v00 = u00, v01 = u01, v10 = u10, v11 = u11;
            if (iter < 17) {                     // prefetch iter+1
                t2h += 8;
                A  = s_A16[t2h];
                Wt = s_W[t2h];
                u00 = *(const uint_t*)(xtbB + (((uint_t)A.x) << 7) + lane4);
                u01 = *(const uint_t*)(xtbB + (((uint_t)A.y) << 7) + lane4);
                u10 = *(const uint_t*)(xtbB + (((uint_t)A.z) << 7) + lane4);
                u11 = *(const uint_t*)(xtbB + (((uint_t)A.w) << 7) + lane4);
            }
            uint_t dst = (uint_t)((t_cur & 15)*(SROW*2) + (t_cur >> 4)*128);
            half2v acc2 = h2(v00) * h2(Wc.x);
            acc2 = __builtin_elementwise_fma(h2(v01), h2(Wc.y), acc2);
            acc2 = __builtin_elementwise_fma(h2(v10), h2(Wc.z), acc2);
            acc2 = __builtin_elementwise_fma(h2(v11), h2(Wc.w), acc2);
            *(uint_t*)(s_sb + dst + lane4) = __builtin_bit_cast(uint_t, acc2);
        }
    }
    __syncthreads();

    // ---- Phase C: wave grp -> o rows [grp*16, +16), 16 pixels ----
    float4v acc = {0.f,0.f,0.f,0.f};
    const ushort_t* arow = wtf + ((size_t)(grp*KS)*64 + lane)*8;
    const ushort_t* brow = s_s + n*SROW + quad*8;
    half8 a_cur = *(const half8*)(arow);
#pragma unroll
    for (int ks = 0; ks < KS; ++ks) {
        half8 a_next = a_cur;
        if (ks < KS-1) a_next = *(const half8*)(arow + (ks+1)*512);
        half8 bf = *(const half8*)(brow + ks*32);
        acc = MFMA16(a_cur, bf, acc);
        a_cur = a_next;
    }

#pragma unroll
    for (int r = 0; r < 4; ++r) {
        int o = grp*16 + quad*4 + r;
        out[(((size_t)b*OUTq + o)*Hq + i)*Wq + j0 + n] = acc[r];
    }
}

// ---------------------------------------------------------------------------
extern "C" void kernel_launch(void* const* d_in, const int* in_sizes, int n_in,
                              void* d_out, int out_size, void* d_ws, size_t ws_size,
                              hipStream_t stream) {
    const float* x     = (const float*)d_in[0];
    const float* off_w = (const float*)d_in[1];
    const float* off_b = (const float*)d_in[2];
    const float* msk_w = (const float*)d_in[3];
    const float* msk_b = (const float*)d_in[4];
    const float* dcn_w = (const float*)d_in[5];
    float* out = (float*)d_out;

    char* ws = (char*)d_ws;
    ushort_t* xt   = (ushort_t*)ws;                  // 13,107,200 B
    ushort_t* wtf  = xt + (size_t)Bq*HWq*64;         //     73,728 B
    ushort_t* cwf2 = wtf + 4*KS*512;                 //     36,864 B

    hipLaunchKernelGGL(k_prep, dim3(HWq/64, Bq), dim3(256), 0, stream,
                       x, dcn_w, off_w, msk_w, xt, wtf, cwf2);
    hipLaunchKernelGGL(k_fused, dim3(Bq*Hq*10), dim3(256), 0, stream,
                       xt, cwf2, off_b, msk_b, wtf, out);
}